// Round 6
// baseline (4724.229 us; speedup 1.0000x reference)
//
#include <hip/hip_runtime.h>

#define TOKENS   32768
#define DIM      256
#define KCB      1024
#define CBOOKS   8
#define NTOK     2048
#define ZQ_ELEMS (TOKENS * DIM)

// numpy pairwise sum of squares for one 256-row: two 128-halves, 8 stride-8
// accumulators each, combine ((r0+r1)+(r2+r3))+((r4+r5)+(r6+r7)), h0+h1.
__device__ float np_pairwise_sumsq_256(const float4* a4) {
  #pragma clang fp contract(off)
  float h[2];
  for (int hh = 0; hh < 2; ++hh) {
    const float4* b = a4 + hh * 32;          // 32 float4 = 128 floats
    float4 v0 = b[0], v1 = b[1];
    float r0 = v0.x * v0.x, r1 = v0.y * v0.y, r2 = v0.z * v0.z, r3 = v0.w * v0.w;
    float r4 = v1.x * v1.x, r5 = v1.y * v1.y, r6 = v1.z * v1.z, r7 = v1.w * v1.w;
    for (int t = 1; t < 16; ++t) {
      float4 w0 = b[2 * t], w1 = b[2 * t + 1];
      r0 = r0 + w0.x * w0.x; r1 = r1 + w0.y * w0.y;
      r2 = r2 + w0.z * w0.z; r3 = r3 + w0.w * w0.w;
      r4 = r4 + w1.x * w1.x; r5 = r5 + w1.y * w1.y;
      r6 = r6 + w1.z * w1.z; r7 = r7 + w1.w * w1.w;
    }
    h[hh] = ((r0 + r1) + (r2 + r3)) + ((r4 + r5) + (r6 + r7));
  }
  return h[0] + h[1];
}

// npyv_muladd on SSE baseline: UNFUSED (a*b)+c, componentwise.
__device__ __forceinline__ float4 f4_muladd(float4 a, float4 b, float4 c) {
  #pragma clang fp contract(off)
  float4 r;
  r.x = a.x * b.x + c.x;
  r.y = a.y * b.y + c.y;
  r.z = a.z * b.z + c.z;
  r.w = a.w * b.w + c.w;
  return r;
}

// |e|^2 for all 8192 codewords, numpy-pairwise order. One thread per row.
__global__ __launch_bounds__(256) void rvq_norms_kernel(
    const float* __restrict__ cb, float* __restrict__ sume) {
  int row = blockIdx.x * 256 + threadIdx.x;          // 0..8191
  sume[row] = np_pairwise_sumsq_256((const float4*)&cb[(size_t)row * DIM]);
}

// |x_res|^2 per token, numpy-pairwise order. One thread per token.
__global__ __launch_bounds__(256) void rvq_sumx_kernel(
    const float* __restrict__ xr, float* __restrict__ sumx) {
  int row = blockIdx.x * 256 + threadIdx.x;          // 0..32767
  sumx[row] = np_pairwise_sumsq_256((const float4*)&xr[(size_t)row * DIM]);
}

// c==0: xr = x_in (bit copy).  c>0: xr = xr - zq (elementwise f32).
__global__ __launch_bounds__(256) void rvq_resid_kernel(
    const float* __restrict__ xin, const float* __restrict__ zq,
    float* __restrict__ xr, int first) {
  #pragma clang fp contract(off)
  int gid = blockIdx.x * 256 + threadIdx.x;          // 2M float4s
  if (first) {
    ((float4*)xr)[gid] = ((const float4*)xin)[gid];
  } else {
    float4 x = ((float4*)xr)[gid];
    float4 z = ((const float4*)zq)[gid];
    float4 o; o.x = x.x - z.x; o.y = x.y - z.y; o.z = x.z - z.z; o.w = x.w - z.w;
    ((float4*)xr)[gid] = o;
  }
}

// Distance + argmin. Dot replicates numpy's einsum
// sum_of_products_contig_contig_outstride0_two at SSE3 baseline:
//   vacc (4 lanes, init 0); per 16-elem block t (q = 4t..4t+3):
//     vacc = muladd(P(4t), muladd(P(4t+1), muladd(P(4t+2), muladd(P(4t+3), vacc))))
//   (high quad enters first, all mul/add UNFUSED); 256 elems = 16 blocks, no tail.
//   dot = (v0+v1)+(v2+v3)   (SSE3 hadd tree)
//   d2  = (sumx - 2*dot) + sume ; argmin first-occurrence.
// Block: 256 thr, tile 32 tokens x 32 ks per kt step (32 steps).
// token = m0 + ty + 16*mi ; k = kt*32 + tx + 16*ni  (ty=tid>>4, tx=tid&15)
__global__ __launch_bounds__(256) void rvq_dist_kernel(
    const float* __restrict__ xr,    // [TOKENS][DIM] current residual
    const float* __restrict__ cbc,   // [KCB][DIM] codebook c
    const float* __restrict__ sume,  // [KCB]
    const float* __restrict__ sumx,  // [TOKENS]
    int* __restrict__ idx_ws,        // [TOKENS]
    float* __restrict__ idxf) {      // index output slab for codebook c
  #pragma clang fp contract(off)
  __shared__ float4 xs[32][64];      // xs[r][q ^ (r&7)]
  __shared__ float4 es[32][64];
  __shared__ float  sm[KCB];

  const int tid = threadIdx.x;
  const int tx  = tid & 15;
  const int ty  = tid >> 4;
  const int m0  = blockIdx.x * 32;
  const float4* xr4 = (const float4*)xr;
  const float4* cb4 = (const float4*)cbc;

  #pragma unroll
  for (int i = 0; i < 4; ++i) sm[i * 256 + tid] = sume[i * 256 + tid];
  #pragma unroll
  for (int jj = 0; jj < 8; ++jj) {
    int g = jj * 256 + tid;
    int r = g >> 6, q = g & 63;
    xs[r][q ^ (r & 7)] = xr4[(size_t)(m0 + r) * 64 + q];
  }
  __syncthreads();

  const float sumx0 = sumx[m0 + ty];
  const float sumx1 = sumx[m0 + ty + 16];
  const int sy = ty & 7, sx = tx & 7;

  float rv[2] = {3.0e38f, 3.0e38f};
  int   ri[2] = {0x7fffffff, 0x7fffffff};

  for (int kt = 0; kt < 32; ++kt) {
    if (kt) __syncthreads();
    #pragma unroll
    for (int jj = 0; jj < 8; ++jj) {
      int g = jj * 256 + tid;
      int r = g >> 6, q = g & 63;
      es[r][q ^ (r & 7)] = cb4[(size_t)(kt * 32 + r) * 64 + q];
    }
    __syncthreads();

    float4 v00 = {0,0,0,0}, v01 = {0,0,0,0}, v10 = {0,0,0,0}, v11 = {0,0,0,0};
    for (int t = 0; t < 16; ++t) {             // 16-element npyv blocks
      float4 xa[4], xb[4], ea[4], eb[4];
      #pragma unroll
      for (int i = 0; i < 4; ++i) {
        int q = 4 * t + i;
        xa[i] = xs[ty][q ^ sy];
        xb[i] = xs[ty + 16][q ^ sy];
        ea[i] = es[tx][q ^ sx];
        eb[i] = es[tx + 16][q ^ sx];
      }
      // reverse-chained: high quad first, unfused mul+add each step
      v00 = f4_muladd(xa[0], ea[0], f4_muladd(xa[1], ea[1],
            f4_muladd(xa[2], ea[2], f4_muladd(xa[3], ea[3], v00))));
      v01 = f4_muladd(xa[0], eb[0], f4_muladd(xa[1], eb[1],
            f4_muladd(xa[2], eb[2], f4_muladd(xa[3], eb[3], v01))));
      v10 = f4_muladd(xb[0], ea[0], f4_muladd(xb[1], ea[1],
            f4_muladd(xb[2], ea[2], f4_muladd(xb[3], ea[3], v10))));
      v11 = f4_muladd(xb[0], eb[0], f4_muladd(xb[1], eb[1],
            f4_muladd(xb[2], eb[2], f4_muladd(xb[3], eb[3], v11))));
    }

    #pragma unroll
    for (int mi = 0; mi < 2; ++mi) {
      float sxv = mi ? sumx1 : sumx0;
      #pragma unroll
      for (int ni = 0; ni < 2; ++ni) {
        float4 s = mi ? (ni ? v11 : v10) : (ni ? v01 : v00);
        float dot = (s.x + s.y) + (s.z + s.w);  // SSE3 hadd tree
        int   k   = kt * 32 + 16 * ni + tx;
        float d2  = (sxv - 2.0f * dot) + sm[k];
        if (d2 < rv[mi] || (d2 == rv[mi] && k < ri[mi])) { rv[mi] = d2; ri[mi] = k; }
      }
    }
  }

  // reduce across the 16 tx lanes (same wave)
  #pragma unroll
  for (int mi = 0; mi < 2; ++mi) {
    float bv = rv[mi]; int bi = ri[mi];
    #pragma unroll
    for (int off = 1; off < 16; off <<= 1) {
      float ov = __shfl_xor(bv, off, 64);
      int   oi = __shfl_xor(bi, off, 64);
      if (ov < bv || (ov == bv && oi < bi)) { bv = ov; bi = oi; }
    }
    if (tx == 0) {
      int token = m0 + ty + 16 * mi;
      idx_ws[token] = bi;
      int b = token >> 11;
      int n = token & (NTOK - 1);
      idxf[(size_t)b * (CBOOKS * NTOK) + n] = (float)bi;
    }
  }
}

// z_q update with code_sg perturbation: zi = xr + (e - xr); zq = zq + zi.
__global__ __launch_bounds__(256) void rvq_zq_kernel(
    const float* __restrict__ xr, const float* __restrict__ cbc,
    const int* __restrict__ idx_ws, float* __restrict__ zq, int first) {
  #pragma clang fp contract(off)
  int gid   = blockIdx.x * 256 + threadIdx.x;        // 2M float4s
  int token = gid >> 6;
  int q     = gid & 63;
  int idx   = idx_ws[token];
  float4 e = ((const float4*)cbc)[(size_t)idx * 64 + q];
  float4 x = ((const float4*)xr)[gid];
  float4 zi;
  zi.x = x.x + (e.x - x.x); zi.y = x.y + (e.y - x.y);
  zi.z = x.z + (e.z - x.z); zi.w = x.w + (e.w - x.w);
  float4 zo;
  if (first) { zo = zi; }
  else {
    float4 z = ((float4*)zq)[gid];
    zo.x = z.x + zi.x; zo.y = z.y + zi.y; zo.z = z.z + zi.z; zo.w = z.w + zi.w;
  }
  ((float4*)zq)[gid] = zo;
}

// ---------------------------------------------------------------------------
extern "C" void kernel_launch(void* const* d_in, const int* in_sizes, int n_in,
                              void* d_out, int out_size, void* d_ws, size_t ws_size,
                              hipStream_t stream) {
  const float* x_in = (const float*)d_in[0];
  const float* cbs  = (const float*)d_in[1];
  float* zq      = (float*)d_out;
  float* idxbase = (float*)d_out + ZQ_ELEMS;

  char* ws = (char*)d_ws;
  float* sume   = (float*)ws;                        // 32 KB
  float* sumx   = (float*)(ws + (64 << 10));         // 128 KB
  int*   idx_ws = (int*)(ws + (256 << 10));          // 128 KB
  float* xr     = (float*)(ws + (1 << 20));          // 32 MB

  rvq_norms_kernel<<<32, 256, 0, stream>>>(cbs, sume);
  for (int c = 0; c < CBOOKS; ++c) {
    const float* cbc = cbs + (size_t)c * KCB * DIM;
    rvq_resid_kernel<<<8192, 256, 0, stream>>>(x_in, zq, xr, c == 0);
    rvq_sumx_kernel<<<128, 256, 0, stream>>>(xr, sumx);
    rvq_dist_kernel<<<1024, 256, 0, stream>>>(
        xr, cbc, sume + (size_t)c * KCB, sumx, idx_ws,
        idxbase + (size_t)c * NTOK);
    rvq_zq_kernel<<<8192, 256, 0, stream>>>(xr, cbc, idx_ws, zq, c == 0);
  }
}

// Round 7
// 2607.206 us; speedup vs baseline: 1.8120x; 1.8120x over previous
//
#include <hip/hip_runtime.h>

#define TOKENS   32768
#define DIM      256
#define KCB      1024
#define CBOOKS   8
#define NTOK     2048
#define ZQ_ELEMS (TOKENS * DIM)
#define EPS_GAP  2.0e-2f

#define MT 128
#define NT 128
#define KC 32

// numpy pairwise sum of squares for one 256-row (verified bit-exact, r6).
__device__ float np_pairwise_sumsq_256(const float4* a4) {
  #pragma clang fp contract(off)
  float h[2];
  for (int hh = 0; hh < 2; ++hh) {
    const float4* b = a4 + hh * 32;
    float4 v0 = b[0], v1 = b[1];
    float r0 = v0.x * v0.x, r1 = v0.y * v0.y, r2 = v0.z * v0.z, r3 = v0.w * v0.w;
    float r4 = v1.x * v1.x, r5 = v1.y * v1.y, r6 = v1.z * v1.z, r7 = v1.w * v1.w;
    for (int t = 1; t < 16; ++t) {
      float4 w0 = b[2 * t], w1 = b[2 * t + 1];
      r0 = r0 + w0.x * w0.x; r1 = r1 + w0.y * w0.y;
      r2 = r2 + w0.z * w0.z; r3 = r3 + w0.w * w0.w;
      r4 = r4 + w1.x * w1.x; r5 = r5 + w1.y * w1.y;
      r6 = r6 + w1.z * w1.z; r7 = r7 + w1.w * w1.w;
    }
    h[hh] = ((r0 + r1) + (r2 + r3)) + ((r4 + r5) + (r6 + r7));
  }
  return h[0] + h[1];
}

// npyv_muladd at SSE baseline: UNFUSED (a*b)+c componentwise (verified, r6).
__device__ __forceinline__ float4 f4_muladd(float4 a, float4 b, float4 c) {
  #pragma clang fp contract(off)
  float4 r;
  r.x = a.x * b.x + c.x;
  r.y = a.y * b.y + c.y;
  r.z = a.z * b.z + c.z;
  r.w = a.w * b.w + c.w;
  return r;
}

// |e|^2 all 8192 codewords, numpy order. One thread per row.
__global__ __launch_bounds__(256) void rvq_norms_kernel(
    const float* __restrict__ cb, float* __restrict__ sume) {
  int row = blockIdx.x * 256 + threadIdx.x;
  sume[row] = np_pairwise_sumsq_256((const float4*)&cb[(size_t)row * DIM]);
}

// |x_res|^2 per token, numpy order. One thread per token.
__global__ __launch_bounds__(256) void rvq_sumx_kernel(
    const float* __restrict__ xr, float* __restrict__ sumx) {
  int row = blockIdx.x * 256 + threadIdx.x;
  sumx[row] = np_pairwise_sumsq_256((const float4*)&xr[(size_t)row * DIM]);
}

// ---------------------------------------------------------------------------
// FMA screen GEMM: key = sume[k] - 2*dot_fma. Tracks exhaustive best/second
// per token within this 128-k tile; partial (v1, i1, v2) -> part[ntile][tok].
// Tiles: 128 tokens x 128 ks x K-chunks of 32 dims. 256 thr, 8x8 reg tile.
// LDS transposed [dim][row] so inner-loop ds_read_b128 offsets are immediate.
// ---------------------------------------------------------------------------
__global__ __launch_bounds__(256, 4) void rvq_screen_kernel(
    const float* __restrict__ xr,    // [TOKENS][DIM] residual this pass
    const float* __restrict__ cbc,   // [KCB][DIM] codebook c
    const float* __restrict__ sume,  // [KCB]
    float4* __restrict__ part) {     // [KCB/NT][TOKENS] (v1, i1, v2, -)
  __shared__ float xT[KC][MT + 4];
  __shared__ float eT[KC][NT + 4];

  const int tid = threadIdx.x;
  const int tx  = tid & 15;          // k-group: ks tx*8 .. tx*8+7
  const int ty  = tid >> 4;          // token-group: rows ty*8 .. ty*8+7
  const int mtile = blockIdx.x >> 3;
  const int ntile = blockIdx.x & 7;
  const int m0 = mtile * MT;
  const int n0 = ntile * NT;
  const float4* x4 = (const float4*)xr;
  const float4* e4 = (const float4*)cbc;

  float acc[8][8] = {};

  for (int kc = 0; kc < 8; ++kc) {
    if (kc) __syncthreads();
    #pragma unroll
    for (int jj = 0; jj < 4; ++jj) {           // x: 128 rows x 8 f4
      int item = jj * 256 + tid;
      int r = item >> 3, q4 = item & 7;
      float4 v = x4[(size_t)(m0 + r) * 64 + kc * 8 + q4];
      xT[q4 * 4 + 0][r] = v.x; xT[q4 * 4 + 1][r] = v.y;
      xT[q4 * 4 + 2][r] = v.z; xT[q4 * 4 + 3][r] = v.w;
    }
    #pragma unroll
    for (int jj = 0; jj < 4; ++jj) {           // e: 128 rows x 8 f4
      int item = jj * 256 + tid;
      int r = item >> 3, q4 = item & 7;
      float4 v = e4[(size_t)(n0 + r) * 64 + kc * 8 + q4];
      eT[q4 * 4 + 0][r] = v.x; eT[q4 * 4 + 1][r] = v.y;
      eT[q4 * 4 + 2][r] = v.z; eT[q4 * 4 + 3][r] = v.w;
    }
    __syncthreads();
    #pragma unroll
    for (int kk = 0; kk < KC; ++kk) {
      float4 xv0 = *(const float4*)&xT[kk][ty * 8];
      float4 xv1 = *(const float4*)&xT[kk][ty * 8 + 4];
      float4 ev0 = *(const float4*)&eT[kk][tx * 8];
      float4 ev1 = *(const float4*)&eT[kk][tx * 8 + 4];
      float xm[8] = {xv0.x, xv0.y, xv0.z, xv0.w, xv1.x, xv1.y, xv1.z, xv1.w};
      float em[8] = {ev0.x, ev0.y, ev0.z, ev0.w, ev1.x, ev1.y, ev1.z, ev1.w};
      #pragma unroll
      for (int mi = 0; mi < 8; ++mi)
        #pragma unroll
        for (int ni = 0; ni < 8; ++ni)
          acc[mi][ni] = fmaf(xm[mi], em[ni], acc[mi][ni]);
    }
  }

  float se[8];
  #pragma unroll
  for (int ni = 0; ni < 8; ++ni) se[ni] = sume[n0 + tx * 8 + ni];

  #pragma unroll
  for (int mi = 0; mi < 8; ++mi) {
    float v1 = 3.0e38f, v2 = 3.0e38f; int i1 = 0x7fffffff;
    #pragma unroll
    for (int ni = 0; ni < 8; ++ni) {
      float key = fmaf(-2.0f, acc[mi][ni], se[ni]);
      int   k   = n0 + tx * 8 + ni;
      if (key < v1) { v2 = v1; v1 = key; i1 = k; }
      else          { v2 = fminf(v2, key); }
    }
    #pragma unroll
    for (int off = 1; off < 16; off <<= 1) {
      float ov1 = __shfl_xor(v1, off, 64);
      int   oi1 = __shfl_xor(i1, off, 64);
      float ov2 = __shfl_xor(v2, off, 64);
      if (ov1 < v1 || (ov1 == v1 && oi1 < i1)) { v2 = fminf(ov2, v1); v1 = ov1; i1 = oi1; }
      else { v2 = fminf(v2, fminf(ov1, ov2)); }
    }
    if (tx == 0) {
      int token = m0 + ty * 8 + mi;
      part[(size_t)ntile * TOKENS + token] =
          make_float4(v1, __int_as_float(i1), v2, 0.0f);
    }
  }
}

// Merge 8 n-tile partials -> provisional index + near-tie flag. Thread/token.
__global__ __launch_bounds__(256) void rvq_merge_kernel(
    const float4* __restrict__ part, int* __restrict__ idx_ws,
    int* __restrict__ flag_ws, float* __restrict__ idxf) {
  int token = blockIdx.x * 256 + threadIdx.x;
  float v1 = 3.0e38f, v2 = 3.0e38f; int i1 = 0x7fffffff;
  #pragma unroll
  for (int j = 0; j < 8; ++j) {
    float4 p = part[(size_t)j * TOKENS + token];
    float ov1 = p.x, ov2 = p.z; int oi1 = __float_as_int(p.y);
    if (ov1 < v1 || (ov1 == v1 && oi1 < i1)) { v2 = fminf(ov2, v1); v1 = ov1; i1 = oi1; }
    else { v2 = fminf(v2, fminf(ov1, ov2)); }
  }
  idx_ws[token]  = i1;
  flag_ws[token] = (v2 - v1 < EPS_GAP) ? 1 : 0;
  int b = token >> 11, n = token & (NTOK - 1);
  idxf[(size_t)b * (CBOOKS * NTOK) + n] = (float)i1;
}

// Exact numpy rescan for flagged tokens (rare). Block owns 128 tokens.
__global__ __launch_bounds__(256) void rvq_fixup_kernel(
    const float* __restrict__ xr, const float* __restrict__ cbc,
    const float* __restrict__ sume, const float* __restrict__ sumx,
    const int* __restrict__ flag_ws, int* __restrict__ idx_ws,
    float* __restrict__ idxf) {
  #pragma clang fp contract(off)
  __shared__ float xs[DIM];
  __shared__ float redv[4];
  __shared__ int   redi[4];
  const int tid = threadIdx.x;

  for (int ml = 0; ml < 128; ++ml) {
    int token = blockIdx.x * 128 + ml;
    if (!flag_ws[token]) continue;             // uniform branch
    if (tid < 64)
      ((float4*)xs)[tid] = ((const float4*)xr)[(size_t)token * 64 + tid];
    __syncthreads();
    float sxv = sumx[token];
    float bv = 3.0e38f; int bi = 0x7fffffff;
    #pragma unroll
    for (int kk = 0; kk < 4; ++kk) {
      int k = kk * 256 + tid;
      float4 vacc = {0.f, 0.f, 0.f, 0.f};
      for (int t = 0; t < 16; ++t) {
        float4 ab = vacc;
        #pragma unroll
        for (int j = 3; j >= 0; --j) {         // reverse-chained npyv block
          float4 xq = *(const float4*)&xs[t * 16 + j * 4];
          float4 eq = *(const float4*)&cbc[(size_t)k * DIM + t * 16 + j * 4];
          ab = f4_muladd(xq, eq, ab);
        }
        vacc = ab;
      }
      float dot = (vacc.x + vacc.y) + (vacc.z + vacc.w);
      float d2  = (sxv - 2.0f * dot) + sume[k];
      if (d2 < bv || (d2 == bv && k < bi)) { bv = d2; bi = k; }
    }
    #pragma unroll
    for (int off = 1; off < 64; off <<= 1) {
      float ov = __shfl_xor(bv, off, 64);
      int   oi = __shfl_xor(bi, off, 64);
      if (ov < bv || (ov == bv && oi < bi)) { bv = ov; bi = oi; }
    }
    int w = tid >> 6;
    if ((tid & 63) == 0) { redv[w] = bv; redi[w] = bi; }
    __syncthreads();
    if (tid == 0) {
      #pragma unroll
      for (int ww = 1; ww < 4; ++ww)
        if (redv[ww] < bv || (redv[ww] == bv && redi[ww] < bi)) { bv = redv[ww]; bi = redi[ww]; }
      idx_ws[token] = bi;
      int b = token >> 11, n = token & (NTOK - 1);
      idxf[(size_t)b * (CBOOKS * NTOK) + n] = (float)bi;
    }
    __syncthreads();
  }
}

// Fused: zi = xr + (e - xr); zq += zi; xr_next = xr - zq_new. Bit-exact (r6).
__global__ __launch_bounds__(256) void rvq_zq_resid_kernel(
    const float* __restrict__ xsrc, const float* __restrict__ cbc,
    const int* __restrict__ idx_ws, float* __restrict__ zq,
    float* __restrict__ xdst, int first, int last) {
  #pragma clang fp contract(off)
  int gid   = blockIdx.x * 256 + threadIdx.x;  // 2M float4s
  int token = gid >> 6;
  int q     = gid & 63;
  int idx   = idx_ws[token];
  float4 e = ((const float4*)cbc)[(size_t)idx * 64 + q];
  float4 x = ((const float4*)xsrc)[gid];
  float4 zi;
  zi.x = x.x + (e.x - x.x); zi.y = x.y + (e.y - x.y);
  zi.z = x.z + (e.z - x.z); zi.w = x.w + (e.w - x.w);
  float4 zo;
  if (first) { zo = zi; }
  else {
    float4 z = ((float4*)zq)[gid];
    zo.x = z.x + zi.x; zo.y = z.y + zi.y; zo.z = z.z + zi.z; zo.w = z.w + zi.w;
  }
  ((float4*)zq)[gid] = zo;
  if (!last) {
    float4 xn;
    xn.x = x.x - zo.x; xn.y = x.y - zo.y; xn.z = x.z - zo.z; xn.w = x.w - zo.w;
    ((float4*)xdst)[gid] = xn;
  }
}

// ---------------------------------------------------------------------------
extern "C" void kernel_launch(void* const* d_in, const int* in_sizes, int n_in,
                              void* d_out, int out_size, void* d_ws, size_t ws_size,
                              hipStream_t stream) {
  const float* x_in = (const float*)d_in[0];
  const float* cbs  = (const float*)d_in[1];
  float* zq      = (float*)d_out;
  float* idxbase = (float*)d_out + ZQ_ELEMS;

  char* ws = (char*)d_ws;
  float*  sume    = (float*)ws;                      // 32 KB
  float*  sumx    = (float*)(ws + (64 << 10));       // 128 KB
  int*    idx_ws  = (int*)(ws + (256 << 10));        // 128 KB
  int*    flag_ws = (int*)(ws + (448 << 10));        // 128 KB
  float4* part    = (float4*)(ws + (1 << 20));       // 4 MB
  float*  xr      = (float*)(ws + (8 << 20));        // 32 MB

  rvq_norms_kernel<<<32, 256, 0, stream>>>(cbs, sume);
  for (int c = 0; c < CBOOKS; ++c) {
    const float* src = (c == 0) ? x_in : xr;
    const float* cbc = cbs + (size_t)c * KCB * DIM;
    float* idxf = idxbase + (size_t)c * NTOK;
    rvq_sumx_kernel<<<128, 256, 0, stream>>>(src, sumx);
    rvq_screen_kernel<<<2048, 256, 0, stream>>>(
        src, cbc, sume + (size_t)c * KCB, part);
    rvq_merge_kernel<<<128, 256, 0, stream>>>(part, idx_ws, flag_ws, idxf);
    rvq_fixup_kernel<<<256, 256, 0, stream>>>(
        src, cbc, sume + (size_t)c * KCB, sumx, flag_ws, idx_ws, idxf);
    rvq_zq_resid_kernel<<<8192, 256, 0, stream>>>(
        src, cbc, idx_ws, zq, xr, c == 0, c == CBOOKS - 1);
  }
}